// Round 6
// baseline (243.301 us; speedup 1.0000x reference)
//
#include <hip/hip_runtime.h>
#include <cstdint>
#include <math.h>

#define DEV __device__ __forceinline__

typedef unsigned int u32;
typedef unsigned short u16;
typedef __attribute__((ext_vector_type(4))) float f32x4;
typedef __attribute__((ext_vector_type(4))) u32 u32x4;
typedef __attribute__((ext_vector_type(2))) u32 u32x2;
typedef __attribute__((ext_vector_type(8))) __bf16 bf16x8;

static_assert(sizeof(bf16x8) == 16, "bf16x8 must be 16B");

static constexpr int Tn = 2048, Cn = 1024;
static constexpr int Mrows = 2 * Tn;  // 4096
// Q scale: 1/sqrt(64)/TEMP * log2(e)  (softmax runs in exp2 domain)
static constexpr float QSCALE2 = 0.125f * 1.44269504088896f;

DEV u16 f2bf_rne(float f) {
  u32 u = __builtin_bit_cast(u32, f);
  u32 r = u + 0x7fffu + ((u >> 16) & 1u);
  return (u16)(r >> 16);
}
DEV float bf2f(u16 h) {
  u32 u = ((u32)h) << 16;
  return __builtin_bit_cast(float, u);
}
DEV u32 pack2bf(float a, float b) {  // a -> low16, b -> high16
  return (u32)f2bf_rne(a) | ((u32)f2bf_rne(b) << 16);
}
// single-instruction packed f32->bf16 (RNE)
DEV u32 cvtpk(float lo, float hi) {
  u32 r;
  asm("v_cvt_pk_bf16_f32 %0, %1, %2" : "=v"(r) : "v"(lo), "v"(hi));
  return r;
}
DEV float fexp2(float x) {
#if __has_builtin(__builtin_amdgcn_exp2f)
  return __builtin_amdgcn_exp2f(x);
#else
  return exp2f(x);
#endif
}

// async 16B global->LDS (wave-uniform base + lane*16 on the LDS side)
DEV void stage16(const void* g, void* l) {
#if __has_builtin(__builtin_amdgcn_global_load_lds)
  __builtin_amdgcn_global_load_lds(
      (__attribute__((address_space(1))) u32*)(uintptr_t)g,
      (__attribute__((address_space(3))) u32*)l, 16, 0, 0);
#else
  *(u32x4*)l = *(const u32x4*)g;
#endif
}

// ---------------- LayerNorm (fp32 in -> bf16 out) ----------------
__global__ __launch_bounds__(256) void ln_kernel(const float* __restrict__ x,
                                                 const float* __restrict__ sc,
                                                 const float* __restrict__ bi,
                                                 u16* __restrict__ xn) {
  int row = blockIdx.x;
  int t = threadIdx.x;
  const float* xr = x + (size_t)row * Cn;
  f32x4 v = *(const f32x4*)(xr + t * 4);
  float s = v.x + v.y + v.z + v.w;
  float s2 = v.x * v.x + v.y * v.y + v.z * v.z + v.w * v.w;
#pragma unroll
  for (int off = 1; off < 64; off <<= 1) {
    s += __shfl_xor(s, off);
    s2 += __shfl_xor(s2, off);
  }
  __shared__ float red[8];
  if ((t & 63) == 0) {
    red[(t >> 6) * 2] = s;
    red[(t >> 6) * 2 + 1] = s2;
  }
  __syncthreads();
  s = red[0] + red[2] + red[4] + red[6];
  s2 = red[1] + red[3] + red[5] + red[7];
  float mean = s * (1.0f / Cn);
  float var = s2 * (1.0f / Cn) - mean * mean;
  float rstd = rsqrtf(var + 1e-6f);
  f32x4 g = *(const f32x4*)(sc + t * 4);
  f32x4 b = *(const f32x4*)(bi + t * 4);
  u32 lo = pack2bf((v.x - mean) * rstd * g.x + b.x, (v.y - mean) * rstd * g.y + b.y);
  u32 hi = pack2bf((v.z - mean) * rstd * g.z + b.z, (v.w - mean) * rstd * g.w + b.w);
  u32x2 pack = {lo, hi};
  *(u32x2*)(xn + (size_t)row * Cn + t * 4) = pack;
}

// -------- transpose + cast both weights: fp32 [1024][Cc] -> bf16 [Cc][1024] --
__global__ __launch_bounds__(256) void transpose_cast2(const float* __restrict__ qkv_w,
                                                       u16* __restrict__ wqkv,
                                                       const float* __restrict__ proj_w,
                                                       u16* __restrict__ wproj) {
  __shared__ float tile[32][33];
  int bx = blockIdx.x;
  const float* src;
  u16* dst;
  int Cc;
  if (bx < 96) {
    src = qkv_w; dst = wqkv; Cc = 3072;
  } else {
    src = proj_w; dst = wproj; Cc = 1024; bx -= 96;
  }
  int tx = threadIdx.x, ty = threadIdx.y;
  int c0 = bx * 32, r0 = blockIdx.y * 32;
#pragma unroll
  for (int k = 0; k < 4; ++k)
    tile[ty + 8 * k][tx] = src[(size_t)(r0 + ty + 8 * k) * Cc + c0 + tx];
  __syncthreads();
#pragma unroll
  for (int k = 0; k < 4; ++k)
    dst[(size_t)(c0 + ty + 8 * k) * 1024 + r0 + tx] = f2bf_rne(tile[tx][ty + 8 * k]);
}

// ---- V^T prepass: qkvm V region [token][h*64+d] -> vt[bh][d][t] bf16 ----
__global__ __launch_bounds__(256) void vt_prep(const u16* __restrict__ qkvm,
                                               u16* __restrict__ vt) {
  __shared__ u16 tile[32][33];
  int bh = blockIdx.z;
  int b = bh >> 4, h = bh & 15;
  int t0 = blockIdx.x * 32, d0 = blockIdx.y * 32;
  int tx = threadIdx.x, ty = threadIdx.y;
#pragma unroll
  for (int k = 0; k < 4; ++k)
    tile[ty + 8 * k][tx] =
        qkvm[(size_t)(b * Tn + t0 + ty + 8 * k) * 3072 + 2 * Cn + h * 64 + d0 + tx];
  __syncthreads();
#pragma unroll
  for (int k = 0; k < 4; ++k)
    vt[((size_t)bh * 64 + d0 + ty + 8 * k) * 2048 + t0 + tx] = tile[tx][ty + 8 * k];
}

// ---------------- GEMM: A bf16 [M][K] x Bt bf16 [N][K] + bias -> C [M][N] ----
template <bool OUT_F32, bool QKV_SCALE>
__global__ __launch_bounds__(256, 3) void gemm_kernel(const u16* __restrict__ A,
                                                      const u16* __restrict__ Bt,
                                                      const float* __restrict__ bias,
                                                      void* __restrict__ Cout,
                                                      int Nsz, int Ksz) {
  __shared__ u16 As[128 * 32];
  __shared__ u16 Bs[128 * 32];
  int t = threadIdx.x;
  int l = t & 63, w = t >> 6;
  int quad = l >> 4, c16 = l & 15;
  int wm = w & 1, wn = w >> 1;
  int m0 = blockIdx.y * 128, n0 = blockIdx.x * 128;

  f32x4 acc[4][4];
#pragma unroll
  for (int mt = 0; mt < 4; ++mt)
#pragma unroll
    for (int nt = 0; nt < 4; ++nt) acc[mt][nt] = (f32x4){0.f, 0.f, 0.f, 0.f};

  for (int kk = 0; kk < Ksz; kk += 32) {
#pragma unroll
    for (int i = 0; i < 2; ++i) {
      int c = t + i * 256;
      int m = c >> 2, k8 = (c & 3) ^ ((m >> 1) & 3);
      stage16(A + (size_t)(m0 + m) * Ksz + kk + k8 * 8, (char*)As + c * 16);
    }
#pragma unroll
    for (int i = 0; i < 2; ++i) {
      int c = t + i * 256;
      int n = c >> 2, k8 = (c & 3) ^ ((n >> 1) & 3);
      stage16(Bt + (size_t)(n0 + n) * Ksz + kk + k8 * 8, (char*)Bs + c * 16);
    }
    __syncthreads();
    bf16x8 af[4], bf[4];
#pragma unroll
    for (int mt = 0; mt < 4; ++mt) {
      int m = wm * 64 + mt * 16 + c16;
      int LC = m * 4 + (quad ^ ((m >> 1) & 3));
      af[mt] = *(const bf16x8*)((const char*)As + LC * 16);
    }
#pragma unroll
    for (int nt = 0; nt < 4; ++nt) {
      int n = wn * 64 + nt * 16 + c16;
      int LC = n * 4 + (quad ^ ((n >> 1) & 3));
      bf[nt] = *(const bf16x8*)((const char*)Bs + LC * 16);
    }
#pragma unroll
    for (int mt = 0; mt < 4; ++mt)
#pragma unroll
      for (int nt = 0; nt < 4; ++nt)
        acc[mt][nt] = __builtin_amdgcn_mfma_f32_16x16x32_bf16(af[mt], bf[nt],
                                                              acc[mt][nt], 0, 0, 0);
    __syncthreads();
  }
  // epilogue: C/D layout col=lane&15, row=quad*4+reg
#pragma unroll
  for (int mt = 0; mt < 4; ++mt) {
    int row = m0 + wm * 64 + mt * 16 + quad * 4;
#pragma unroll
    for (int nt = 0; nt < 4; ++nt) {
      int col = n0 + wn * 64 + nt * 16 + c16;
      float bv = bias[col];
      float scale = (QKV_SCALE && col < 1024) ? QSCALE2 : 1.0f;
#pragma unroll
      for (int r = 0; r < 4; ++r) {
        float v = (acc[mt][nt][r] + bv) * scale;
        if (OUT_F32)
          ((float*)Cout)[(size_t)(row + r) * Nsz + col] = v;
        else
          ((u16*)Cout)[(size_t)(row + r) * Nsz + col] = f2bf_rne(v);
      }
    }
  }
}

// ---------------- causal flash attention, paired q-tiles ----------------
// 512-thread blocks: waves 0-3 work q-tile qtA, waves 4-7 work qtB=qtA-1;
// both share one K/V staging (same k-range under causality). Chunk table:
// {qtA, k0, kcnt, slotA} + slotB[]; slot<0 = direct write, else partial slot.
// 15 chunks x 32 bh = 480 blocks, all resident at 2 blocks/CU.
__constant__ int4 chunk_tab[15] = {
    {15, 0, 6, 0},  {15, 6, 5, 1},  {15, 11, 5, 2},
    {13, 0, 7, 6},  {13, 7, 7, 7},
    {11, 0, 4, 10}, {11, 4, 4, 11}, {11, 8, 4, 12},
    {9, 0, 5, 16},  {9, 5, 5, 17},
    {7, 0, 4, 20},  {7, 4, 4, 21},
    {5, 0, 6, -1},  {3, 0, 4, -1},  {1, 0, 2, -1}};
__constant__ int chunk_slotB[15] = {3, 4, 5, 8, 9, 13, 14, 15,
                                    18, 19, 22, 23, -1, -1, -1};

// per-qt combine info (qt 6..15): {first partial slot, n splits}
__constant__ int2 comb_tab[10] = {{22, 2}, {20, 2}, {18, 2}, {16, 2}, {13, 3},
                                  {10, 3}, {8, 2},  {6, 2},  {3, 3},  {0, 3}};

// qkv bf16 [4096][3072] (Q pre-scaled by 0.125*log2e), vt bf16 [32][64][2048]
// -> attn bf16 [4096][1024] (direct) or partials Op/ml. Softmax in exp2 domain.
// Structure (best known from R2/R5): K+V double-buffered, staged together at
// top of iter for tile t+1, ONE barrier per tile; P relayout fully in
// registers (cvt_pk + permlane32/16_swap), zero LDS bank conflicts.
// This round: q-tile pairing -> 8 waves share staging; 16 waves/CU
// (VGPR 112 <= 128 -> 4 waves/SIMD; LDS 2x64KB = 128 <= 160KB); K/V HBM
// traffic per q-row halves. B-group waves skip compute (wave-uniform) on the
// final iteration where kt > qtB.
__global__ __launch_bounds__(512, 2) void flash_kernel(const u16* __restrict__ qkv,
                                                       const u16* __restrict__ vt,
                                                       u16* __restrict__ aout,
                                                       u16* __restrict__ Op,
                                                       float* __restrict__ ml) {
  int cid = blockIdx.x >> 5;
  int4 ck = chunk_tab[cid];
  int bh = blockIdx.x & 31;
  int k0 = ck.y, nk = ck.z;
  int b = bh >> 4, h = bh & 15;
  int t = threadIdx.x, l = t & 63, w = t >> 6;
  int g = w >> 2, wl = w & 3;          // g: 0 = tile A, 1 = tile B
  int qt = ck.x - g;
  int slot = g ? chunk_slotB[cid] : ck.w;
  int quad = l >> 4, c16 = l & 15;
  int q0 = qt * 128;

  __shared__ u16 Ks[2][128 * 64];  // [key][d] swizzled 16B chunks, dbuf (32 KiB)
  __shared__ u16 Vs[2][64 * 128];  // [d][key] swizzled 16B chunks, dbuf (32 KiB)

  // Q fragments (B-operand layout), pre-scaled in GEMM epilogue
  bf16x8 qf[2][2];
#pragma unroll
  for (int nt = 0; nt < 2; ++nt)
#pragma unroll
    for (int ks = 0; ks < 2; ++ks)
      qf[nt][ks] = *(const bf16x8*)(qkv +
          (size_t)(b * Tn + q0 + wl * 32 + nt * 16 + c16) * 3072 +
          h * 64 + ks * 32 + quad * 8);

  float mrow[2] = {-1e30f, -1e30f};
  float lrow[2] = {0.f, 0.f};
  f32x4 o[2][4];
#pragma unroll
  for (int mq = 0; mq < 2; ++mq)
#pragma unroll
    for (int dt = 0; dt < 4; ++dt) o[mq][dt] = (f32x4){0.f, 0.f, 0.f, 0.f};

  // async stage of one K tile + one V tile into buffer `buf` (512 threads)
  auto stageKV = [&](int buf, int kt) {
#pragma unroll
    for (int i = 0; i < 2; ++i) {
      int c = t + i * 512;
      int key = c >> 3, d8 = (c & 7) ^ (key & 7);
      stage16(qkv + (size_t)(b * Tn + kt * 128 + key) * 3072 + Cn + h * 64 + d8 * 8,
              (char*)Ks[buf] + c * 16);
    }
#pragma unroll
    for (int i = 0; i < 2; ++i) {
      int c = t + i * 512;
      int d = c >> 4, k8 = (c & 15) ^ (d & 15);
      stage16(vt + ((size_t)bh * 64 + d) * 2048 + kt * 128 + k8 * 8,
              (char*)Vs[buf] + c * 16);
    }
  };

  // prologue: stage tile k0 into buffer 0
  stageKV(0, k0);
  __syncthreads();

  for (int it = 0; it < nk; ++it) {
    int kt = k0 + it;
    // prefetch next K+V tile; the end-of-iteration barrier's vmcnt(0) drain
    // lands a full iteration after issue, so it costs ~nothing
    if (it + 1 < nk) stageKV((it + 1) & 1, kt + 1);

    // B-group waves have no work when kt > qt (trailing iteration of the
    // pair's shared range) -- wave-uniform skip, barrier still executed.
    if (kt <= qt) {
      const char* Kb = (const char*)Ks[it & 1];
      const char* Vb = (const char*)Vs[it & 1];

      // S^T = K . Q^T  (A=K from LDS, B=Q^T from regs); m=key, n=q
      f32x4 s[8][2];
#pragma unroll
      for (int mt = 0; mt < 8; ++mt)
#pragma unroll
        for (int nt = 0; nt < 2; ++nt) s[mt][nt] = (f32x4){0.f, 0.f, 0.f, 0.f};
#pragma unroll
      for (int mt = 0; mt < 8; ++mt) {
#pragma unroll
        for (int ks = 0; ks < 2; ++ks) {
          int key = mt * 16 + c16;
          int d8 = ks * 4 + quad;
          int LC = key * 8 + (d8 ^ (key & 7));
          bf16x8 kf = *(const bf16x8*)(Kb + LC * 16);
#pragma unroll
          for (int nt = 0; nt < 2; ++nt)
            s[mt][nt] = __builtin_amdgcn_mfma_f32_16x16x32_bf16(kf, qf[nt][ks],
                                                                s[mt][nt], 0, 0, 0);
        }
      }
      // diagonal causal mask
      if (kt == qt) {
#pragma unroll
        for (int mt = 0; mt < 8; ++mt)
#pragma unroll
          for (int nt = 0; nt < 2; ++nt)
#pragma unroll
            for (int r = 0; r < 4; ++r) {
              int key = kt * 128 + mt * 16 + quad * 4 + r;
              int q = q0 + wl * 32 + nt * 16 + c16;
              if (key > q) s[mt][nt][r] = -1e30f;
            }
      }
      // online softmax, exp2 domain (stats per q = c16, replicated over
      // quads). defer-rescale: if no row's tile-max exceeds m+6, keep old m
      // (exact math; P bounded by 2^6) and skip the alpha pass entirely.
      float alph[2];
      int needv[2];
#pragma unroll
      for (int nt = 0; nt < 2; ++nt) {
        float m8[8];
#pragma unroll
        for (int mt = 0; mt < 8; ++mt)
          m8[mt] = fmaxf(fmaxf(s[mt][nt][0], s[mt][nt][1]),
                         fmaxf(s[mt][nt][2], s[mt][nt][3]));
        float rm = fmaxf(fmaxf(fmaxf(m8[0], m8[1]), fmaxf(m8[2], m8[3])),
                         fmaxf(fmaxf(m8[4], m8[5]), fmaxf(m8[6], m8[7])));
        rm = fmaxf(rm, __shfl_xor(rm, 16));
        rm = fmaxf(rm, __shfl_xor(rm, 32));
        int need = __any(rm > mrow[nt] + 6.0f);
        needv[nt] = need;
        float mnew = need ? fmaxf(mrow[nt], rm) : mrow[nt];
        alph[nt] = need ? fexp2(mrow[nt] - mnew) : 1.0f;
        mrow[nt] = mnew;
        float part[8];
#pragma unroll
        for (int mt = 0; mt < 8; ++mt) {
          float e0 = fexp2(s[mt][nt][0] - mnew);
          float e1 = fexp2(s[mt][nt][1] - mnew);
          float e2 = fexp2(s[mt][nt][2] - mnew);
          float e3 = fexp2(s[mt][nt][3] - mnew);
          s[mt][nt][0] = e0; s[mt][nt][1] = e1;
          s[mt][nt][2] = e2; s[mt][nt][3] = e3;
          part[mt] = (e0 + e1) + (e2 + e3);
        }
        float rs = ((part[0] + part[1]) + (part[2] + part[3])) +
                   ((part[4] + part[5]) + (part[6] + part[7]));
        rs += __shfl_xor(rs, 16);
        rs += __shfl_xor(rs, 32);
        lrow[nt] = lrow[nt] * alph[nt] + rs;
      }
      // rescale O by alpha (alpha lives per q=c16; O rows are q=quad*4+r)
#pragma unroll
      for (int mq = 0; mq < 2; ++mq)
        if (needv[mq]) {
#pragma unroll
          for (int r = 0; r < 4; ++r) {
            float a = __shfl(alph[mq], quad * 4 + r);
#pragma unroll
            for (int dt = 0; dt < 4; ++dt) o[mq][dt][r] *= a;
          }
        }
      // PV in four 32-key quarters; P^T (C/D layout) -> A-frag layout done
      // fully in registers via the 4x4 cross-quad permlane exchange.
#pragma unroll
      for (int ksq = 0; ksq < 4; ++ksq) {
        bf16x8 pa[2];
#pragma unroll
        for (int nt = 0; nt < 2; ++nt) {
          u32 A = cvtpk(s[2 * ksq][nt][0], s[2 * ksq][nt][1]);
          u32 B = cvtpk(s[2 * ksq][nt][2], s[2 * ksq][nt][3]);
          u32 C = cvtpk(s[2 * ksq + 1][nt][0], s[2 * ksq + 1][nt][1]);
          u32 D = cvtpk(s[2 * ksq + 1][nt][2], s[2 * ksq + 1][nt][3]);
          asm volatile("v_permlane32_swap_b32 %0, %1" : "+v"(A), "+v"(C));
          asm volatile("v_permlane32_swap_b32 %0, %1" : "+v"(B), "+v"(D));
          asm volatile("v_permlane16_swap_b32 %0, %1" : "+v"(A), "+v"(C));
          asm volatile("v_permlane16_swap_b32 %0, %1" : "+v"(B), "+v"(D));
          u32x4 pk = {A, B, C, D};
          pa[nt] = __builtin_bit_cast(bf16x8, pk);
        }
#pragma unroll
        for (int dt = 0; dt < 4; ++dt) {
          int d = dt * 16 + c16;
          int vc = d * 16 + ((ksq * 4 + quad) ^ (d & 15));
          bf16x8 vf = *(const bf16x8*)(Vb + vc * 16);
#pragma unroll
          for (int mq = 0; mq < 2; ++mq)
            o[mq][dt] = __builtin_amdgcn_mfma_f32_16x16x32_bf16(pa[mq], vf,
                                                                o[mq][dt], 0, 0, 0);
        }
      }
    }
    __syncthreads();
  }

  float linv[2] = {1.0f / lrow[0], 1.0f / lrow[1]};
  if (slot < 0) {
    // direct output
#pragma unroll
    for (int mq = 0; mq < 2; ++mq)
#pragma unroll
      for (int r = 0; r < 4; ++r) {
        float li = __shfl(linv[mq], quad * 4 + r);
        int q = q0 + wl * 32 + mq * 16 + quad * 4 + r;
#pragma unroll
        for (int dt = 0; dt < 4; ++dt)
          aout[(size_t)(b * Tn + q) * 1024 + h * 64 + dt * 16 + c16] =
              f2bf_rne(o[mq][dt][r] * li);
      }
  } else {
    // partial: normalized O + (m, l) per row (m in log2 domain)
    int ps = slot * 32 + bh;
#pragma unroll
    for (int mq = 0; mq < 2; ++mq)
#pragma unroll
      for (int r = 0; r < 4; ++r) {
        float li = __shfl(linv[mq], quad * 4 + r);
        int qr = wl * 32 + mq * 16 + quad * 4 + r;
#pragma unroll
        for (int dt = 0; dt < 4; ++dt)
          Op[((size_t)ps * 128 + qr) * 64 + dt * 16 + c16] =
              f2bf_rne(o[mq][dt][r] * li);
      }
    if (quad == 0) {
#pragma unroll
      for (int nt = 0; nt < 2; ++nt) {
        int qr = wl * 32 + nt * 16 + c16;
        ml[((size_t)ps * 128 + qr) * 2] = mrow[nt];
        ml[((size_t)ps * 128 + qr) * 2 + 1] = lrow[nt];
      }
    }
  }
}

// ---------------- combine split partials (m in log2 domain, n-way) ----------
__global__ __launch_bounds__(256) void combine_kernel(const u16* __restrict__ Op,
                                                      const float* __restrict__ ml,
                                                      u16* __restrict__ aout) {
  int qt = 6 + (blockIdx.x >> 5);
  int bh = blockIdx.x & 31;
  int b = bh >> 4, h = bh & 15;
  int2 cb = comb_tab[qt - 6];
  int base = cb.x, n = cb.y;
  int d = threadIdx.x & 63, rq = threadIdx.x >> 6;
  for (int r = 0; r < 32; ++r) {
    int row = rq * 32 + r;
    float mv[3], lv[3], ov[3];
#pragma unroll
    for (int i = 0; i < 3; ++i) {
      int ps = (base + (i < n ? i : 0)) * 32 + bh;
      bool valid = i < n;
      mv[i] = valid ? ml[((size_t)ps * 128 + row) * 2] : -1e30f;
      lv[i] = valid ? ml[((size_t)ps * 128 + row) * 2 + 1] : 0.f;
      ov[i] = valid ? bf2f(Op[((size_t)ps * 128 + row) * 64 + d]) : 0.f;
    }
    float M = fmaxf(fmaxf(mv[0], mv[1]), mv[2]);
    float w0 = fexp2(mv[0] - M) * lv[0];
    float w1 = fexp2(mv[1] - M) * lv[1];
    float w2 = fexp2(mv[2] - M) * lv[2];
    float inv = 1.0f / (w0 + w1 + w2);
    aout[(size_t)(b * Tn + qt * 128 + row) * 1024 + h * 64 + d] =
        f2bf_rne((w0 * ov[0] + w1 * ov[1] + w2 * ov[2]) * inv);
  }
}

extern "C" void kernel_launch(void* const* d_in, const int* in_sizes, int n_in,
                              void* d_out, int out_size, void* d_ws, size_t ws_size,
                              hipStream_t stream) {
  const float* x = (const float*)d_in[0];
  // d_in[1] = causal mask: tril, implemented analytically — never read
  const float* ln_s = (const float*)d_in[2];
  const float* ln_b = (const float*)d_in[3];
  const float* qkv_w = (const float*)d_in[4];
  const float* qkv_b = (const float*)d_in[5];
  const float* proj_w = (const float*)d_in[6];
  const float* proj_b = (const float*)d_in[7];
  float* out = (float*)d_out;
  char* ws = (char*)d_ws;

  u16* xn = (u16*)ws;                       // 8 MiB  [4096][1024]
  u16* wqkv = (u16*)(ws + (8ull << 20));    // 6 MiB  [3072][1024]
  u16* wproj = (u16*)(ws + (14ull << 20));  // 2 MiB  [1024][1024]
  u16* qkvm = (u16*)(ws + (16ull << 20));   // 24 MiB [4096][3072]
  u16* attn = (u16*)(ws + (40ull << 20));   // 8 MiB  [4096][1024]
  u16* vt = (u16*)(ws + (48ull << 20));     // 8 MiB  [32][64][2048]
  // partials alias xn/wqkv (dead after QKV GEMM); wproj at 14MiB stays live:
  u16* Op = (u16*)ws;                        // 12 MiB  [24*32][128][64] bf16
  float* ml = (float*)(ws + (12ull << 20));  // 768 KiB [24*32][128][2] f32

  ln_kernel<<<Mrows, 256, 0, stream>>>(x, ln_s, ln_b, xn);
  transpose_cast2<<<dim3(128, 32), dim3(32, 8), 0, stream>>>(qkv_w, wqkv, proj_w,
                                                             wproj);
  gemm_kernel<false, true><<<dim3(24, 32), 256, 0, stream>>>(xn, wqkv, qkv_b, qkvm,
                                                             3072, 1024);
  vt_prep<<<dim3(64, 2, 32), dim3(32, 8), 0, stream>>>(qkvm, vt);
  flash_kernel<<<480, 512, 0, stream>>>(qkvm, vt, attn, Op, ml);
  combine_kernel<<<320, 256, 0, stream>>>(Op, ml, attn);
  gemm_kernel<true, false><<<dim3(8, 32), 256, 0, stream>>>(attn, wproj, proj_b, out,
                                                            1024, 1024);
}

// Round 7
// 239.055 us; speedup vs baseline: 1.0178x; 1.0178x over previous
//
#include <hip/hip_runtime.h>
#include <cstdint>
#include <math.h>

#define DEV __device__ __forceinline__

typedef unsigned int u32;
typedef unsigned short u16;
typedef __attribute__((ext_vector_type(4))) float f32x4;
typedef __attribute__((ext_vector_type(4))) u32 u32x4;
typedef __attribute__((ext_vector_type(2))) u32 u32x2;
typedef __attribute__((ext_vector_type(8))) __bf16 bf16x8;

static_assert(sizeof(bf16x8) == 16, "bf16x8 must be 16B");

static constexpr int Tn = 2048, Cn = 1024;
static constexpr int Mrows = 2 * Tn;  // 4096
// Q scale: 1/sqrt(64)/TEMP * log2(e)  (softmax runs in exp2 domain)
static constexpr float QSCALE2 = 0.125f * 1.44269504088896f;

DEV u16 f2bf_rne(float f) {
  u32 u = __builtin_bit_cast(u32, f);
  u32 r = u + 0x7fffu + ((u >> 16) & 1u);
  return (u16)(r >> 16);
}
DEV float bf2f(u16 h) {
  u32 u = ((u32)h) << 16;
  return __builtin_bit_cast(float, u);
}
DEV u32 pack2bf(float a, float b) {  // a -> low16, b -> high16
  return (u32)f2bf_rne(a) | ((u32)f2bf_rne(b) << 16);
}
// single-instruction packed f32->bf16 (RNE)
DEV u32 cvtpk(float lo, float hi) {
  u32 r;
  asm("v_cvt_pk_bf16_f32 %0, %1, %2" : "=v"(r) : "v"(lo), "v"(hi));
  return r;
}
DEV float fexp2(float x) {
#if __has_builtin(__builtin_amdgcn_exp2f)
  return __builtin_amdgcn_exp2f(x);
#else
  return exp2f(x);
#endif
}

// async 16B global->LDS (wave-uniform base + lane*16 on the LDS side)
DEV void stage16(const void* g, void* l) {
#if __has_builtin(__builtin_amdgcn_global_load_lds)
  __builtin_amdgcn_global_load_lds(
      (__attribute__((address_space(1))) u32*)(uintptr_t)g,
      (__attribute__((address_space(3))) u32*)l, 16, 0, 0);
#else
  *(u32x4*)l = *(const u32x4*)g;
#endif
}

// ---------------- LayerNorm (fp32 in -> bf16 out) ----------------
__global__ __launch_bounds__(256) void ln_kernel(const float* __restrict__ x,
                                                 const float* __restrict__ sc,
                                                 const float* __restrict__ bi,
                                                 u16* __restrict__ xn) {
  int row = blockIdx.x;
  int t = threadIdx.x;
  const float* xr = x + (size_t)row * Cn;
  f32x4 v = *(const f32x4*)(xr + t * 4);
  float s = v.x + v.y + v.z + v.w;
  float s2 = v.x * v.x + v.y * v.y + v.z * v.z + v.w * v.w;
#pragma unroll
  for (int off = 1; off < 64; off <<= 1) {
    s += __shfl_xor(s, off);
    s2 += __shfl_xor(s2, off);
  }
  __shared__ float red[8];
  if ((t & 63) == 0) {
    red[(t >> 6) * 2] = s;
    red[(t >> 6) * 2 + 1] = s2;
  }
  __syncthreads();
  s = red[0] + red[2] + red[4] + red[6];
  s2 = red[1] + red[3] + red[5] + red[7];
  float mean = s * (1.0f / Cn);
  float var = s2 * (1.0f / Cn) - mean * mean;
  float rstd = rsqrtf(var + 1e-6f);
  f32x4 g = *(const f32x4*)(sc + t * 4);
  f32x4 b = *(const f32x4*)(bi + t * 4);
  u32 lo = pack2bf((v.x - mean) * rstd * g.x + b.x, (v.y - mean) * rstd * g.y + b.y);
  u32 hi = pack2bf((v.z - mean) * rstd * g.z + b.z, (v.w - mean) * rstd * g.w + b.w);
  u32x2 pack = {lo, hi};
  *(u32x2*)(xn + (size_t)row * Cn + t * 4) = pack;
}

// -------- transpose + cast both weights: fp32 [1024][Cc] -> bf16 [Cc][1024] --
__global__ __launch_bounds__(256) void transpose_cast2(const float* __restrict__ qkv_w,
                                                       u16* __restrict__ wqkv,
                                                       const float* __restrict__ proj_w,
                                                       u16* __restrict__ wproj) {
  __shared__ float tile[32][33];
  int bx = blockIdx.x;
  const float* src;
  u16* dst;
  int Cc;
  if (bx < 96) {
    src = qkv_w; dst = wqkv; Cc = 3072;
  } else {
    src = proj_w; dst = wproj; Cc = 1024; bx -= 96;
  }
  int tx = threadIdx.x, ty = threadIdx.y;
  int c0 = bx * 32, r0 = blockIdx.y * 32;
#pragma unroll
  for (int k = 0; k < 4; ++k)
    tile[ty + 8 * k][tx] = src[(size_t)(r0 + ty + 8 * k) * Cc + c0 + tx];
  __syncthreads();
#pragma unroll
  for (int k = 0; k < 4; ++k)
    dst[(size_t)(c0 + ty + 8 * k) * 1024 + r0 + tx] = f2bf_rne(tile[tx][ty + 8 * k]);
}

// ---- V^T prepass: qkvm V region [token][h*64+d] -> vt[bh][d][t] bf16 ----
__global__ __launch_bounds__(256) void vt_prep(const u16* __restrict__ qkvm,
                                               u16* __restrict__ vt) {
  __shared__ u16 tile[32][33];
  int bh = blockIdx.z;
  int b = bh >> 4, h = bh & 15;
  int t0 = blockIdx.x * 32, d0 = blockIdx.y * 32;
  int tx = threadIdx.x, ty = threadIdx.y;
#pragma unroll
  for (int k = 0; k < 4; ++k)
    tile[ty + 8 * k][tx] =
        qkvm[(size_t)(b * Tn + t0 + ty + 8 * k) * 3072 + 2 * Cn + h * 64 + d0 + tx];
  __syncthreads();
#pragma unroll
  for (int k = 0; k < 4; ++k)
    vt[((size_t)bh * 64 + d0 + ty + 8 * k) * 2048 + t0 + tx] = tile[tx][ty + 8 * k];
}

// ---------------- GEMM: A bf16 [M][K] x Bt bf16 [N][K] + bias -> C [M][N] ----
template <bool OUT_F32, bool QKV_SCALE>
__global__ __launch_bounds__(256, 3) void gemm_kernel(const u16* __restrict__ A,
                                                      const u16* __restrict__ Bt,
                                                      const float* __restrict__ bias,
                                                      void* __restrict__ Cout,
                                                      int Nsz, int Ksz) {
  __shared__ u16 As[128 * 32];
  __shared__ u16 Bs[128 * 32];
  int t = threadIdx.x;
  int l = t & 63, w = t >> 6;
  int quad = l >> 4, c16 = l & 15;
  int wm = w & 1, wn = w >> 1;
  int m0 = blockIdx.y * 128, n0 = blockIdx.x * 128;

  f32x4 acc[4][4];
#pragma unroll
  for (int mt = 0; mt < 4; ++mt)
#pragma unroll
    for (int nt = 0; nt < 4; ++nt) acc[mt][nt] = (f32x4){0.f, 0.f, 0.f, 0.f};

  for (int kk = 0; kk < Ksz; kk += 32) {
#pragma unroll
    for (int i = 0; i < 2; ++i) {
      int c = t + i * 256;
      int m = c >> 2, k8 = (c & 3) ^ ((m >> 1) & 3);
      stage16(A + (size_t)(m0 + m) * Ksz + kk + k8 * 8, (char*)As + c * 16);
    }
#pragma unroll
    for (int i = 0; i < 2; ++i) {
      int c = t + i * 256;
      int n = c >> 2, k8 = (c & 3) ^ ((n >> 1) & 3);
      stage16(Bt + (size_t)(n0 + n) * Ksz + kk + k8 * 8, (char*)Bs + c * 16);
    }
    __syncthreads();
    bf16x8 af[4], bf[4];
#pragma unroll
    for (int mt = 0; mt < 4; ++mt) {
      int m = wm * 64 + mt * 16 + c16;
      int LC = m * 4 + (quad ^ ((m >> 1) & 3));
      af[mt] = *(const bf16x8*)((const char*)As + LC * 16);
    }
#pragma unroll
    for (int nt = 0; nt < 4; ++nt) {
      int n = wn * 64 + nt * 16 + c16;
      int LC = n * 4 + (quad ^ ((n >> 1) & 3));
      bf[nt] = *(const bf16x8*)((const char*)Bs + LC * 16);
    }
#pragma unroll
    for (int mt = 0; mt < 4; ++mt)
#pragma unroll
      for (int nt = 0; nt < 4; ++nt)
        acc[mt][nt] = __builtin_amdgcn_mfma_f32_16x16x32_bf16(af[mt], bf[nt],
                                                              acc[mt][nt], 0, 0, 0);
    __syncthreads();
  }
  // epilogue: C/D layout col=lane&15, row=quad*4+reg
#pragma unroll
  for (int mt = 0; mt < 4; ++mt) {
    int row = m0 + wm * 64 + mt * 16 + quad * 4;
#pragma unroll
    for (int nt = 0; nt < 4; ++nt) {
      int col = n0 + wn * 64 + nt * 16 + c16;
      float bv = bias[col];
      float scale = (QKV_SCALE && col < 1024) ? QSCALE2 : 1.0f;
#pragma unroll
      for (int r = 0; r < 4; ++r) {
        float v = (acc[mt][nt][r] + bv) * scale;
        if (OUT_F32)
          ((float*)Cout)[(size_t)(row + r) * Nsz + col] = v;
        else
          ((u16*)Cout)[(size_t)(row + r) * Nsz + col] = f2bf_rne(v);
      }
    }
  }
}

// ---------------- causal flash attention, balanced chunks ----------------
// chunk table: {qt, k0, kcnt, slot} in 128-key units; slot<0 = direct write,
// else partial slot. Inner loop runs 2 sub-tiles (64 keys) per unit.
__constant__ int4 chunk_tab[31] = {
    {15, 0, 6, 0},  {10, 0, 6, 15}, {5, 0, 6, -1},
    {15, 6, 5, 1},  {15, 11, 5, 2}, {14, 0, 5, 3},  {14, 5, 5, 4},
    {14, 10, 5, 5}, {13, 0, 5, 6},  {13, 5, 5, 7},  {12, 0, 5, 9},
    {10, 6, 5, 16}, {9, 0, 5, 17},  {9, 5, 5, 18},  {8, 0, 5, 19},
    {4, 0, 5, -1},
    {13, 10, 4, 8}, {12, 5, 4, 10}, {12, 9, 4, 11}, {11, 0, 4, 12},
    {11, 4, 4, 13}, {11, 8, 4, 14}, {8, 5, 4, 20},  {7, 0, 4, 21},
    {7, 4, 4, 22},  {6, 0, 4, 23},  {3, 0, 4, -1},
    {6, 4, 3, 24},  {2, 0, 3, -1},
    {1, 0, 2, -1},
    {0, 0, 1, -1}};

// per-qt combine info (qt 6..15): {first partial slot, n splits}
__constant__ int2 comb_tab[10] = {{23, 2}, {21, 2}, {19, 2}, {17, 2}, {15, 2},
                                  {12, 3}, {9, 3},  {6, 3},  {3, 3},  {0, 3}};

// qkv bf16 [4096][3072] (Q pre-scaled by 0.125*log2e), vt bf16 [32][64][2048]
// -> attn bf16 [4096][1024] (direct) or partials Op/ml. Softmax in exp2 domain.
// Occupancy play, corrected: R3 proved 40KB LDS lifts measured occupancy to
// 28% but its launch_bounds(256,4) reg-cap forced spill (VGPR 64, +19MB
// scratch) and regressed. Now Ps is gone (R5's in-register P relayout), so
// 64-key sub-tiles with K AND V double-buffered need only 32KB LDS; s[4][2]
// frees ~32 VGPR vs R5's s[8][2] (~100 total, under the natural 128 cap for
// 4 waves/SIMD). 4-5 blocks/CU = 16-20 waves/CU. Loop = R5's proven shape:
// stage sub-tile t+1 at top of iter t, ONE barrier per sub-tile.
__global__ __launch_bounds__(256, 2) void flash_kernel(const u16* __restrict__ qkv,
                                                       const u16* __restrict__ vt,
                                                       u16* __restrict__ aout,
                                                       u16* __restrict__ Op,
                                                       float* __restrict__ ml) {
  int4 ck = chunk_tab[blockIdx.x >> 5];
  int bh = blockIdx.x & 31;
  int qt = ck.x, slot = ck.w;
  int sb0 = ck.y * 2, nst = ck.z * 2;  // sub-tile base/count (64-key units)
  int b = bh >> 4, h = bh & 15;
  int t = threadIdx.x, l = t & 63, w = t >> 6;
  int quad = l >> 4, c16 = l & 15;
  int q0 = qt * 128;

  __shared__ u16 Ks[2][64 * 64];  // [key][d] swizzled 16B chunks, dbuf (16 KiB)
  __shared__ u16 Vs[2][64 * 64];  // [d][key] swizzled 16B chunks, dbuf (16 KiB)

  // Q fragments (B-operand layout), pre-scaled in GEMM epilogue
  bf16x8 qf[2][2];
#pragma unroll
  for (int nt = 0; nt < 2; ++nt)
#pragma unroll
    for (int ks = 0; ks < 2; ++ks)
      qf[nt][ks] = *(const bf16x8*)(qkv +
          (size_t)(b * Tn + q0 + w * 32 + nt * 16 + c16) * 3072 +
          h * 64 + ks * 32 + quad * 8);

  float mrow[2] = {-1e30f, -1e30f};
  float lrow[2] = {0.f, 0.f};
  f32x4 o[2][4];
#pragma unroll
  for (int mq = 0; mq < 2; ++mq)
#pragma unroll
    for (int dt = 0; dt < 4; ++dt) o[mq][dt] = (f32x4){0.f, 0.f, 0.f, 0.f};

  // async stage of one 64-key K sub-tile + V sub-tile into buffer `buf`
  auto stageKV = [&](int buf, int sb) {
    int kb = sb * 64;
#pragma unroll
    for (int i = 0; i < 2; ++i) {
      int c = t + i * 256;
      int key = c >> 3, d8 = (c & 7) ^ (key & 7);
      stage16(qkv + (size_t)(b * Tn + kb + key) * 3072 + Cn + h * 64 + d8 * 8,
              (char*)Ks[buf] + c * 16);
    }
#pragma unroll
    for (int i = 0; i < 2; ++i) {
      int c = t + i * 256;
      int d = c >> 3, k8 = (c & 7) ^ (d & 7);
      stage16(vt + ((size_t)bh * 64 + d) * 2048 + kb + k8 * 8,
              (char*)Vs[buf] + c * 16);
    }
  };

  // prologue: stage sub-tile sb0 into buffer 0
  stageKV(0, sb0);
  __syncthreads();

  for (int st = 0; st < nst; ++st) {
    int kb = (sb0 + st) * 64;
    // prefetch next sub-tile; the end-of-iteration barrier's vmcnt(0) drain
    // lands a full sub-tile after issue, so it costs ~nothing
    if (st + 1 < nst) stageKV((st + 1) & 1, sb0 + st + 1);
    const char* Kb = (const char*)Ks[st & 1];
    const char* Vb = (const char*)Vs[st & 1];

    // S^T = K . Q^T  (A=K from LDS, B=Q^T from regs); m=key, n=q
    f32x4 s[4][2];
#pragma unroll
    for (int mt = 0; mt < 4; ++mt)
#pragma unroll
      for (int nt = 0; nt < 2; ++nt) s[mt][nt] = (f32x4){0.f, 0.f, 0.f, 0.f};
#pragma unroll
    for (int mt = 0; mt < 4; ++mt) {
#pragma unroll
      for (int ks = 0; ks < 2; ++ks) {
        int key = mt * 16 + c16;
        int d8 = ks * 4 + quad;
        int LC = key * 8 + (d8 ^ (key & 7));
        bf16x8 kf = *(const bf16x8*)(Kb + LC * 16);
#pragma unroll
        for (int nt = 0; nt < 2; ++nt)
          s[mt][nt] = __builtin_amdgcn_mfma_f32_16x16x32_bf16(kf, qf[nt][ks],
                                                              s[mt][nt], 0, 0, 0);
      }
    }
    // causal mask: only sub-tiles at/above the diagonal row block need it
    if (kb >= q0) {
#pragma unroll
      for (int mt = 0; mt < 4; ++mt)
#pragma unroll
        for (int nt = 0; nt < 2; ++nt)
#pragma unroll
          for (int r = 0; r < 4; ++r) {
            int key = kb + mt * 16 + quad * 4 + r;
            int q = q0 + w * 32 + nt * 16 + c16;
            if (key > q) s[mt][nt][r] = -1e30f;
          }
    }
    // online softmax, exp2 domain (stats per q = c16, replicated over quads).
    // defer-rescale: if no row's tile-max exceeds m+6, keep old m (exact math;
    // P bounded by 2^6) and skip the alpha pass entirely.
    float alph[2];
    int needv[2];
#pragma unroll
    for (int nt = 0; nt < 2; ++nt) {
      float m4[4];
#pragma unroll
      for (int mt = 0; mt < 4; ++mt)
        m4[mt] = fmaxf(fmaxf(s[mt][nt][0], s[mt][nt][1]),
                       fmaxf(s[mt][nt][2], s[mt][nt][3]));
      float rm = fmaxf(fmaxf(m4[0], m4[1]), fmaxf(m4[2], m4[3]));
      rm = fmaxf(rm, __shfl_xor(rm, 16));
      rm = fmaxf(rm, __shfl_xor(rm, 32));
      int need = __any(rm > mrow[nt] + 6.0f);
      needv[nt] = need;
      float mnew = need ? fmaxf(mrow[nt], rm) : mrow[nt];
      alph[nt] = need ? fexp2(mrow[nt] - mnew) : 1.0f;
      mrow[nt] = mnew;
      float part[4];
#pragma unroll
      for (int mt = 0; mt < 4; ++mt) {
        float e0 = fexp2(s[mt][nt][0] - mnew);
        float e1 = fexp2(s[mt][nt][1] - mnew);
        float e2 = fexp2(s[mt][nt][2] - mnew);
        float e3 = fexp2(s[mt][nt][3] - mnew);
        s[mt][nt][0] = e0; s[mt][nt][1] = e1;
        s[mt][nt][2] = e2; s[mt][nt][3] = e3;
        part[mt] = (e0 + e1) + (e2 + e3);
      }
      float rs = (part[0] + part[1]) + (part[2] + part[3]);
      rs += __shfl_xor(rs, 16);
      rs += __shfl_xor(rs, 32);
      lrow[nt] = lrow[nt] * alph[nt] + rs;
    }
    // rescale O by alpha (alpha lives per q=c16; O rows are q=quad*4+r)
#pragma unroll
    for (int mq = 0; mq < 2; ++mq)
      if (needv[mq]) {
#pragma unroll
        for (int r = 0; r < 4; ++r) {
          float a = __shfl(alph[mq], quad * 4 + r);
#pragma unroll
          for (int dt = 0; dt < 4; ++dt) o[mq][dt][r] *= a;
        }
      }
    // PV in two 32-key halves; P^T (C/D layout) -> A-frag layout fully in
    // registers via the 4x4 cross-quad permlane exchange (R5, verified).
#pragma unroll
    for (int ksq = 0; ksq < 2; ++ksq) {
      bf16x8 pa[2];
#pragma unroll
      for (int nt = 0; nt < 2; ++nt) {
        u32 A = cvtpk(s[2 * ksq][nt][0], s[2 * ksq][nt][1]);
        u32 B = cvtpk(s[2 * ksq][nt][2], s[2 * ksq][nt][3]);
        u32 C = cvtpk(s[2 * ksq + 1][nt][0], s[2 * ksq + 1][nt][1]);
        u32 D = cvtpk(s[2 * ksq + 1][nt][2], s[2 * ksq + 1][nt][3]);
        asm volatile("v_permlane32_swap_b32 %0, %1" : "+v"(A), "+v"(C));
        asm volatile("v_permlane32_swap_b32 %0, %1" : "+v"(B), "+v"(D));
        asm volatile("v_permlane16_swap_b32 %0, %1" : "+v"(A), "+v"(C));
        asm volatile("v_permlane16_swap_b32 %0, %1" : "+v"(B), "+v"(D));
        u32x4 pk = {A, B, C, D};
        pa[nt] = __builtin_bit_cast(bf16x8, pk);
      }
#pragma unroll
      for (int dt = 0; dt < 4; ++dt) {
        int d = dt * 16 + c16;
        int vc = d * 8 + ((ksq * 4 + quad) ^ (d & 7));
        bf16x8 vf = *(const bf16x8*)(Vb + vc * 16);
#pragma unroll
        for (int mq = 0; mq < 2; ++mq)
          o[mq][dt] = __builtin_amdgcn_mfma_f32_16x16x32_bf16(pa[mq], vf,
                                                              o[mq][dt], 0, 0, 0);
      }
    }
    __syncthreads();
  }

  float linv[2] = {1.0f / lrow[0], 1.0f / lrow[1]};
  if (slot < 0) {
    // direct output
#pragma unroll
    for (int mq = 0; mq < 2; ++mq)
#pragma unroll
      for (int r = 0; r < 4; ++r) {
        float li = __shfl(linv[mq], quad * 4 + r);
        int q = q0 + w * 32 + mq * 16 + quad * 4 + r;
#pragma unroll
        for (int dt = 0; dt < 4; ++dt)
          aout[(size_t)(b * Tn + q) * 1024 + h * 64 + dt * 16 + c16] =
              f2bf_rne(o[mq][dt][r] * li);
      }
  } else {
    // partial: normalized O + (m, l) per row (m in log2 domain)
    int ps = slot * 32 + bh;
#pragma unroll
    for (int mq = 0; mq < 2; ++mq)
#pragma unroll
      for (int r = 0; r < 4; ++r) {
        float li = __shfl(linv[mq], quad * 4 + r);
        int qr = w * 32 + mq * 16 + quad * 4 + r;
#pragma unroll
        for (int dt = 0; dt < 4; ++dt)
          Op[((size_t)ps * 128 + qr) * 64 + dt * 16 + c16] =
              f2bf_rne(o[mq][dt][r] * li);
      }
    if (quad == 0) {
#pragma unroll
      for (int nt = 0; nt < 2; ++nt) {
        int qr = w * 32 + nt * 16 + c16;
        ml[((size_t)ps * 128 + qr) * 2] = mrow[nt];
        ml[((size_t)ps * 128 + qr) * 2 + 1] = lrow[nt];
      }
    }
  }
}

// ---------------- combine split partials (m in log2 domain, n-way) ----------
__global__ __launch_bounds__(256) void combine_kernel(const u16* __restrict__ Op,
                                                      const float* __restrict__ ml,
                                                      u16* __restrict__ aout) {
  int qt = 6 + (blockIdx.x >> 5);
  int bh = blockIdx.x & 31;
  int b = bh >> 4, h = bh & 15;
  int2 cb = comb_tab[qt - 6];
  int base = cb.x, n = cb.y;
  int d = threadIdx.x & 63, rq = threadIdx.x >> 6;
  for (int r = 0; r < 32; ++r) {
    int row = rq * 32 + r;
    float mv[3], lv[3], ov[3];
#pragma unroll
    for (int i = 0; i < 3; ++i) {
      int ps = (base + (i < n ? i : 0)) * 32 + bh;
      bool valid = i < n;
      mv[i] = valid ? ml[((size_t)ps * 128 + row) * 2] : -1e30f;
      lv[i] = valid ? ml[((size_t)ps * 128 + row) * 2 + 1] : 0.f;
      ov[i] = valid ? bf2f(Op[((size_t)ps * 128 + row) * 64 + d]) : 0.f;
    }
    float M = fmaxf(fmaxf(mv[0], mv[1]), mv[2]);
    float w0 = fexp2(mv[0] - M) * lv[0];
    float w1 = fexp2(mv[1] - M) * lv[1];
    float w2 = fexp2(mv[2] - M) * lv[2];
    float inv = 1.0f / (w0 + w1 + w2);
    aout[(size_t)(b * Tn + qt * 128 + row) * 1024 + h * 64 + d] =
        f2bf_rne((w0 * ov[0] + w1 * ov[1] + w2 * ov[2]) * inv);
  }
}

extern "C" void kernel_launch(void* const* d_in, const int* in_sizes, int n_in,
                              void* d_out, int out_size, void* d_ws, size_t ws_size,
                              hipStream_t stream) {
  const float* x = (const float*)d_in[0];
  // d_in[1] = causal mask: tril, implemented analytically — never read
  const float* ln_s = (const float*)d_in[2];
  const float* ln_b = (const float*)d_in[3];
  const float* qkv_w = (const float*)d_in[4];
  const float* qkv_b = (const float*)d_in[5];
  const float* proj_w = (const float*)d_in[6];
  const float* proj_b = (const float*)d_in[7];
  float* out = (float*)d_out;
  char* ws = (char*)d_ws;

  u16* xn = (u16*)ws;                       // 8 MiB  [4096][1024]
  u16* wqkv = (u16*)(ws + (8ull << 20));    // 6 MiB  [3072][1024]
  u16* wproj = (u16*)(ws + (14ull << 20));  // 2 MiB  [1024][1024]
  u16* qkvm = (u16*)(ws + (16ull << 20));   // 24 MiB [4096][3072]
  u16* attn = (u16*)(ws + (40ull << 20));   // 8 MiB  [4096][1024]
  u16* vt = (u16*)(ws + (48ull << 20));     // 8 MiB  [32][64][2048]
  // partials alias xn/wqkv (dead after QKV GEMM):
  u16* Op = (u16*)ws;                        // 12.5 MiB [25*32][128][64] bf16
  float* ml = (float*)(ws + (13ull << 20));  // 800 KiB  [25*32][128][2] f32

  ln_kernel<<<Mrows, 256, 0, stream>>>(x, ln_s, ln_b, xn);
  transpose_cast2<<<dim3(128, 32), dim3(32, 8), 0, stream>>>(qkv_w, wqkv, proj_w,
                                                             wproj);
  gemm_kernel<false, true><<<dim3(24, 32), 256, 0, stream>>>(xn, wqkv, qkv_b, qkvm,
                                                             3072, 1024);
  vt_prep<<<dim3(64, 2, 32), dim3(32, 8), 0, stream>>>(qkvm, vt);
  flash_kernel<<<992, 256, 0, stream>>>(qkvm, vt, attn, Op, ml);
  combine_kernel<<<320, 256, 0, stream>>>(Op, ml, attn);
  gemm_kernel<true, false><<<dim3(8, 32), 256, 0, stream>>>(attn, wproj, proj_b, out,
                                                            1024, 1024);
}

// Round 8
// 233.834 us; speedup vs baseline: 1.0405x; 1.0223x over previous
//
#include <hip/hip_runtime.h>
#include <cstdint>
#include <math.h>

#define DEV __device__ __forceinline__

typedef unsigned int u32;
typedef unsigned short u16;
typedef __attribute__((ext_vector_type(4))) float f32x4;
typedef __attribute__((ext_vector_type(4))) u32 u32x4;
typedef __attribute__((ext_vector_type(2))) u32 u32x2;
typedef __attribute__((ext_vector_type(8))) __bf16 bf16x8;

static_assert(sizeof(bf16x8) == 16, "bf16x8 must be 16B");

static constexpr int Tn = 2048, Cn = 1024;
static constexpr int Mrows = 2 * Tn;  // 4096
// Q scale: 1/sqrt(64)/TEMP * log2(e)  (softmax runs in exp2 domain)
static constexpr float QSCALE2 = 0.125f * 1.44269504088896f;

DEV u16 f2bf_rne(float f) {
  u32 u = __builtin_bit_cast(u32, f);
  u32 r = u + 0x7fffu + ((u >> 16) & 1u);
  return (u16)(r >> 16);
}
DEV float bf2f(u16 h) {
  u32 u = ((u32)h) << 16;
  return __builtin_bit_cast(float, u);
}
DEV u32 pack2bf(float a, float b) {  // a -> low16, b -> high16
  return (u32)f2bf_rne(a) | ((u32)f2bf_rne(b) << 16);
}
// single-instruction packed f32->bf16 (RNE)
DEV u32 cvtpk(float lo, float hi) {
  u32 r;
  asm("v_cvt_pk_bf16_f32 %0, %1, %2" : "=v"(r) : "v"(lo), "v"(hi));
  return r;
}
DEV float fexp2(float x) {
#if __has_builtin(__builtin_amdgcn_exp2f)
  return __builtin_amdgcn_exp2f(x);
#else
  return exp2f(x);
#endif
}

// async 16B global->LDS (wave-uniform base + lane*16 on the LDS side)
DEV void stage16(const void* g, void* l) {
#if __has_builtin(__builtin_amdgcn_global_load_lds)
  __builtin_amdgcn_global_load_lds(
      (__attribute__((address_space(1))) u32*)(uintptr_t)g,
      (__attribute__((address_space(3))) u32*)l, 16, 0, 0);
#else
  *(u32x4*)l = *(const u32x4*)g;
#endif
}

// ---------------- LayerNorm (fp32 in -> bf16 out) ----------------
__global__ __launch_bounds__(256) void ln_kernel(const float* __restrict__ x,
                                                 const float* __restrict__ sc,
                                                 const float* __restrict__ bi,
                                                 u16* __restrict__ xn) {
  int row = blockIdx.x;
  int t = threadIdx.x;
  const float* xr = x + (size_t)row * Cn;
  f32x4 v = *(const f32x4*)(xr + t * 4);
  float s = v.x + v.y + v.z + v.w;
  float s2 = v.x * v.x + v.y * v.y + v.z * v.z + v.w * v.w;
#pragma unroll
  for (int off = 1; off < 64; off <<= 1) {
    s += __shfl_xor(s, off);
    s2 += __shfl_xor(s2, off);
  }
  __shared__ float red[8];
  if ((t & 63) == 0) {
    red[(t >> 6) * 2] = s;
    red[(t >> 6) * 2 + 1] = s2;
  }
  __syncthreads();
  s = red[0] + red[2] + red[4] + red[6];
  s2 = red[1] + red[3] + red[5] + red[7];
  float mean = s * (1.0f / Cn);
  float var = s2 * (1.0f / Cn) - mean * mean;
  float rstd = rsqrtf(var + 1e-6f);
  f32x4 g = *(const f32x4*)(sc + t * 4);
  f32x4 b = *(const f32x4*)(bi + t * 4);
  u32 lo = pack2bf((v.x - mean) * rstd * g.x + b.x, (v.y - mean) * rstd * g.y + b.y);
  u32 hi = pack2bf((v.z - mean) * rstd * g.z + b.z, (v.w - mean) * rstd * g.w + b.w);
  u32x2 pack = {lo, hi};
  *(u32x2*)(xn + (size_t)row * Cn + t * 4) = pack;
}

// -------- transpose + cast both weights: fp32 [1024][Cc] -> bf16 [Cc][1024] --
__global__ __launch_bounds__(256) void transpose_cast2(const float* __restrict__ qkv_w,
                                                       u16* __restrict__ wqkv,
                                                       const float* __restrict__ proj_w,
                                                       u16* __restrict__ wproj) {
  __shared__ float tile[32][33];
  int bx = blockIdx.x;
  const float* src;
  u16* dst;
  int Cc;
  if (bx < 96) {
    src = qkv_w; dst = wqkv; Cc = 3072;
  } else {
    src = proj_w; dst = wproj; Cc = 1024; bx -= 96;
  }
  int tx = threadIdx.x, ty = threadIdx.y;
  int c0 = bx * 32, r0 = blockIdx.y * 32;
#pragma unroll
  for (int k = 0; k < 4; ++k)
    tile[ty + 8 * k][tx] = src[(size_t)(r0 + ty + 8 * k) * Cc + c0 + tx];
  __syncthreads();
#pragma unroll
  for (int k = 0; k < 4; ++k)
    dst[(size_t)(c0 + ty + 8 * k) * 1024 + r0 + tx] = f2bf_rne(tile[tx][ty + 8 * k]);
}

// ---- V^T prepass: qkvm V region [token][h*64+d] -> vt[bh][d][t] bf16 ----
__global__ __launch_bounds__(256) void vt_prep(const u16* __restrict__ qkvm,
                                               u16* __restrict__ vt) {
  __shared__ u16 tile[32][33];
  int bh = blockIdx.z;
  int b = bh >> 4, h = bh & 15;
  int t0 = blockIdx.x * 32, d0 = blockIdx.y * 32;
  int tx = threadIdx.x, ty = threadIdx.y;
#pragma unroll
  for (int k = 0; k < 4; ++k)
    tile[ty + 8 * k][tx] =
        qkvm[(size_t)(b * Tn + t0 + ty + 8 * k) * 3072 + 2 * Cn + h * 64 + d0 + tx];
  __syncthreads();
#pragma unroll
  for (int k = 0; k < 4; ++k)
    vt[((size_t)bh * 64 + d0 + ty + 8 * k) * 2048 + t0 + tx] = tile[tx][ty + 8 * k];
}

// ---------------- GEMM: A bf16 [M][K] x Bt bf16 [N][K] + bias -> C [M][N] ----
// R8: flash-proven pipeline ported here. (1) LDS double-buffer: stage K-step
// k+1 at top of iter k, compute from buf k&1, ONE barrier per K-step (was 2,
// with a zero-cover vmcnt(0) drain each). (2) XCD-aware bijective block
// swizzle (grids are multiples of 8): each XCD gets a contiguous chunk of
// linear ids (4 N-rows sharing 4 A-panels) instead of scattering all M-panels
// across every XCD's L2.
template <bool OUT_F32, bool QKV_SCALE>
__global__ __launch_bounds__(256, 3) void gemm_kernel(const u16* __restrict__ A,
                                                      const u16* __restrict__ Bt,
                                                      const float* __restrict__ bias,
                                                      void* __restrict__ Cout,
                                                      int Nsz, int Ksz) {
  __shared__ u16 As[2][128 * 32];
  __shared__ u16 Bs[2][128 * 32];
  int t = threadIdx.x;
  int l = t & 63, w = t >> 6;
  int quad = l >> 4, c16 = l & 15;
  int wm = w & 1, wn = w >> 1;
  // XCD swizzle: nwg % 8 == 0 (768 and 256), so (bid&7)*cpx + bid/8 is
  // bijective; chunk of cpx consecutive ids lands on one XCD.
  int nx = gridDim.x;
  int bid = blockIdx.y * nx + blockIdx.x;
  int cpx = (nx * gridDim.y) >> 3;
  int swz = (bid & 7) * cpx + (bid >> 3);
  int m0 = (swz / nx) * 128, n0 = (swz % nx) * 128;

  f32x4 acc[4][4];
#pragma unroll
  for (int mt = 0; mt < 4; ++mt)
#pragma unroll
    for (int nt = 0; nt < 4; ++nt) acc[mt][nt] = (f32x4){0.f, 0.f, 0.f, 0.f};

  auto stageAB = [&](int buf, int kk) {
#pragma unroll
    for (int i = 0; i < 2; ++i) {
      int c = t + i * 256;
      int m = c >> 2, k8 = (c & 3) ^ ((m >> 1) & 3);
      stage16(A + (size_t)(m0 + m) * Ksz + kk + k8 * 8, (char*)As[buf] + c * 16);
    }
#pragma unroll
    for (int i = 0; i < 2; ++i) {
      int c = t + i * 256;
      int n = c >> 2, k8 = (c & 3) ^ ((n >> 1) & 3);
      stage16(Bt + (size_t)(n0 + n) * Ksz + kk + k8 * 8, (char*)Bs[buf] + c * 16);
    }
  };

  // prologue: stage K-step 0 into buffer 0
  stageAB(0, 0);
  __syncthreads();

  int nk = Ksz >> 5;
  for (int ik = 0; ik < nk; ++ik) {
    // prefetch next K-step; the end-of-iter barrier's vmcnt(0) drain lands
    // after this iteration's LDS-read + MFMA phase
    if (ik + 1 < nk) stageAB((ik + 1) & 1, (ik + 1) << 5);
    const char* Ab = (const char*)As[ik & 1];
    const char* Bb = (const char*)Bs[ik & 1];

    bf16x8 af[4], bf[4];
#pragma unroll
    for (int mt = 0; mt < 4; ++mt) {
      int m = wm * 64 + mt * 16 + c16;
      int LC = m * 4 + (quad ^ ((m >> 1) & 3));
      af[mt] = *(const bf16x8*)(Ab + LC * 16);
    }
#pragma unroll
    for (int nt = 0; nt < 4; ++nt) {
      int n = wn * 64 + nt * 16 + c16;
      int LC = n * 4 + (quad ^ ((n >> 1) & 3));
      bf[nt] = *(const bf16x8*)(Bb + LC * 16);
    }
#pragma unroll
    for (int mt = 0; mt < 4; ++mt)
#pragma unroll
      for (int nt = 0; nt < 4; ++nt)
        acc[mt][nt] = __builtin_amdgcn_mfma_f32_16x16x32_bf16(af[mt], bf[nt],
                                                              acc[mt][nt], 0, 0, 0);
    __syncthreads();
  }
  // epilogue: C/D layout col=lane&15, row=quad*4+reg
#pragma unroll
  for (int mt = 0; mt < 4; ++mt) {
    int row = m0 + wm * 64 + mt * 16 + quad * 4;
#pragma unroll
    for (int nt = 0; nt < 4; ++nt) {
      int col = n0 + wn * 64 + nt * 16 + c16;
      float bv = bias[col];
      float scale = (QKV_SCALE && col < 1024) ? QSCALE2 : 1.0f;
#pragma unroll
      for (int r = 0; r < 4; ++r) {
        float v = (acc[mt][nt][r] + bv) * scale;
        if (OUT_F32)
          ((float*)Cout)[(size_t)(row + r) * Nsz + col] = v;
        else
          ((u16*)Cout)[(size_t)(row + r) * Nsz + col] = f2bf_rne(v);
      }
    }
  }
}

// ---------------- causal flash attention, balanced chunks ----------------
// chunk table: {qt, k0, kcnt, slot} in 128-key units; slot<0 = direct write,
// else partial slot. Inner loop runs 2 sub-tiles (64 keys) per unit.
__constant__ int4 chunk_tab[31] = {
    {15, 0, 6, 0},  {10, 0, 6, 15}, {5, 0, 6, -1},
    {15, 6, 5, 1},  {15, 11, 5, 2}, {14, 0, 5, 3},  {14, 5, 5, 4},
    {14, 10, 5, 5}, {13, 0, 5, 6},  {13, 5, 5, 7},  {12, 0, 5, 9},
    {10, 6, 5, 16}, {9, 0, 5, 17},  {9, 5, 5, 18},  {8, 0, 5, 19},
    {4, 0, 5, -1},
    {13, 10, 4, 8}, {12, 5, 4, 10}, {12, 9, 4, 11}, {11, 0, 4, 12},
    {11, 4, 4, 13}, {11, 8, 4, 14}, {8, 5, 4, 20},  {7, 0, 4, 21},
    {7, 4, 4, 22},  {6, 0, 4, 23},  {3, 0, 4, -1},
    {6, 4, 3, 24},  {2, 0, 3, -1},
    {1, 0, 2, -1},
    {0, 0, 1, -1}};

// per-qt combine info (qt 6..15): {first partial slot, n splits}
__constant__ int2 comb_tab[10] = {{23, 2}, {21, 2}, {19, 2}, {17, 2}, {15, 2},
                                  {12, 3}, {9, 3},  {6, 3},  {3, 3},  {0, 3}};

// qkv bf16 [4096][3072] (Q pre-scaled by 0.125*log2e), vt bf16 [32][64][2048]
// -> attn bf16 [4096][1024] (direct) or partials Op/ml. Softmax in exp2 domain.
// R7 structure (verified <41us): 64-key sub-tiles, K+V double-buffered in
// 32KB LDS, ONE barrier per sub-tile, in-register P relayout (cvt_pk +
// permlane32/16_swap), zero bank conflicts, VGPR ~100 (no reg-cap: R3 showed
// a forced 128-cap spills).
__global__ __launch_bounds__(256, 2) void flash_kernel(const u16* __restrict__ qkv,
                                                       const u16* __restrict__ vt,
                                                       u16* __restrict__ aout,
                                                       u16* __restrict__ Op,
                                                       float* __restrict__ ml) {
  int4 ck = chunk_tab[blockIdx.x >> 5];
  int bh = blockIdx.x & 31;
  int qt = ck.x, slot = ck.w;
  int sb0 = ck.y * 2, nst = ck.z * 2;  // sub-tile base/count (64-key units)
  int b = bh >> 4, h = bh & 15;
  int t = threadIdx.x, l = t & 63, w = t >> 6;
  int quad = l >> 4, c16 = l & 15;
  int q0 = qt * 128;

  __shared__ u16 Ks[2][64 * 64];  // [key][d] swizzled 16B chunks, dbuf (16 KiB)
  __shared__ u16 Vs[2][64 * 64];  // [d][key] swizzled 16B chunks, dbuf (16 KiB)

  // Q fragments (B-operand layout), pre-scaled in GEMM epilogue
  bf16x8 qf[2][2];
#pragma unroll
  for (int nt = 0; nt < 2; ++nt)
#pragma unroll
    for (int ks = 0; ks < 2; ++ks)
      qf[nt][ks] = *(const bf16x8*)(qkv +
          (size_t)(b * Tn + q0 + w * 32 + nt * 16 + c16) * 3072 +
          h * 64 + ks * 32 + quad * 8);

  float mrow[2] = {-1e30f, -1e30f};
  float lrow[2] = {0.f, 0.f};
  f32x4 o[2][4];
#pragma unroll
  for (int mq = 0; mq < 2; ++mq)
#pragma unroll
    for (int dt = 0; dt < 4; ++dt) o[mq][dt] = (f32x4){0.f, 0.f, 0.f, 0.f};

  // async stage of one 64-key K sub-tile + V sub-tile into buffer `buf`
  auto stageKV = [&](int buf, int sb) {
    int kb = sb * 64;
#pragma unroll
    for (int i = 0; i < 2; ++i) {
      int c = t + i * 256;
      int key = c >> 3, d8 = (c & 7) ^ (key & 7);
      stage16(qkv + (size_t)(b * Tn + kb + key) * 3072 + Cn + h * 64 + d8 * 8,
              (char*)Ks[buf] + c * 16);
    }
#pragma unroll
    for (int i = 0; i < 2; ++i) {
      int c = t + i * 256;
      int d = c >> 3, k8 = (c & 7) ^ (d & 7);
      stage16(vt + ((size_t)bh * 64 + d) * 2048 + kb + k8 * 8,
              (char*)Vs[buf] + c * 16);
    }
  };

  // prologue: stage sub-tile sb0 into buffer 0
  stageKV(0, sb0);
  __syncthreads();

  for (int st = 0; st < nst; ++st) {
    int kb = (sb0 + st) * 64;
    // prefetch next sub-tile; the end-of-iteration barrier's vmcnt(0) drain
    // lands a full sub-tile after issue, so it costs ~nothing
    if (st + 1 < nst) stageKV((st + 1) & 1, sb0 + st + 1);
    const char* Kb = (const char*)Ks[st & 1];
    const char* Vb = (const char*)Vs[st & 1];

    // S^T = K . Q^T  (A=K from LDS, B=Q^T from regs); m=key, n=q
    f32x4 s[4][2];
#pragma unroll
    for (int mt = 0; mt < 4; ++mt)
#pragma unroll
      for (int nt = 0; nt < 2; ++nt) s[mt][nt] = (f32x4){0.f, 0.f, 0.f, 0.f};
#pragma unroll
    for (int mt = 0; mt < 4; ++mt) {
#pragma unroll
      for (int ks = 0; ks < 2; ++ks) {
        int key = mt * 16 + c16;
        int d8 = ks * 4 + quad;
        int LC = key * 8 + (d8 ^ (key & 7));
        bf16x8 kf = *(const bf16x8*)(Kb + LC * 16);
#pragma unroll
        for (int nt = 0; nt < 2; ++nt)
          s[mt][nt] = __builtin_amdgcn_mfma_f32_16x16x32_bf16(kf, qf[nt][ks],
                                                              s[mt][nt], 0, 0, 0);
      }
    }
    // causal mask: only sub-tiles at/above the diagonal row block need it
    if (kb >= q0) {
#pragma unroll
      for (int mt = 0; mt < 4; ++mt)
#pragma unroll
        for (int nt = 0; nt < 2; ++nt)
#pragma unroll
          for (int r = 0; r < 4; ++r) {
            int key = kb + mt * 16 + quad * 4 + r;
            int q = q0 + w * 32 + nt * 16 + c16;
            if (key > q) s[mt][nt][r] = -1e30f;
          }
    }
    // online softmax, exp2 domain (stats per q = c16, replicated over quads).
    // defer-rescale: if no row's tile-max exceeds m+6, keep old m (exact math;
    // P bounded by 2^6) and skip the alpha pass entirely.
    float alph[2];
    int needv[2];
#pragma unroll
    for (int nt = 0; nt < 2; ++nt) {
      float m4[4];
#pragma unroll
      for (int mt = 0; mt < 4; ++mt)
        m4[mt] = fmaxf(fmaxf(s[mt][nt][0], s[mt][nt][1]),
                       fmaxf(s[mt][nt][2], s[mt][nt][3]));
      float rm = fmaxf(fmaxf(m4[0], m4[1]), fmaxf(m4[2], m4[3]));
      rm = fmaxf(rm, __shfl_xor(rm, 16));
      rm = fmaxf(rm, __shfl_xor(rm, 32));
      int need = __any(rm > mrow[nt] + 6.0f);
      needv[nt] = need;
      float mnew = need ? fmaxf(mrow[nt], rm) : mrow[nt];
      alph[nt] = need ? fexp2(mrow[nt] - mnew) : 1.0f;
      mrow[nt] = mnew;
      float part[4];
#pragma unroll
      for (int mt = 0; mt < 4; ++mt) {
        float e0 = fexp2(s[mt][nt][0] - mnew);
        float e1 = fexp2(s[mt][nt][1] - mnew);
        float e2 = fexp2(s[mt][nt][2] - mnew);
        float e3 = fexp2(s[mt][nt][3] - mnew);
        s[mt][nt][0] = e0; s[mt][nt][1] = e1;
        s[mt][nt][2] = e2; s[mt][nt][3] = e3;
        part[mt] = (e0 + e1) + (e2 + e3);
      }
      float rs = (part[0] + part[1]) + (part[2] + part[3]);
      rs += __shfl_xor(rs, 16);
      rs += __shfl_xor(rs, 32);
      lrow[nt] = lrow[nt] * alph[nt] + rs;
    }
    // rescale O by alpha (alpha lives per q=c16; O rows are q=quad*4+r)
#pragma unroll
    for (int mq = 0; mq < 2; ++mq)
      if (needv[mq]) {
#pragma unroll
        for (int r = 0; r < 4; ++r) {
          float a = __shfl(alph[mq], quad * 4 + r);
#pragma unroll
          for (int dt = 0; dt < 4; ++dt) o[mq][dt][r] *= a;
        }
      }
    // PV in two 32-key halves; P^T (C/D layout) -> A-frag layout fully in
    // registers via the 4x4 cross-quad permlane exchange (R5, verified).
#pragma unroll
    for (int ksq = 0; ksq < 2; ++ksq) {
      bf16x8 pa[2];
#pragma unroll
      for (int nt = 0; nt < 2; ++nt) {
        u32 A = cvtpk(s[2 * ksq][nt][0], s[2 * ksq][nt][1]);
        u32 B = cvtpk(s[2 * ksq][nt][2], s[2 * ksq][nt][3]);
        u32 C = cvtpk(s[2 * ksq + 1][nt][0], s[2 * ksq + 1][nt][1]);
        u32 D = cvtpk(s[2 * ksq + 1][nt][2], s[2 * ksq + 1][nt][3]);
        asm volatile("v_permlane32_swap_b32 %0, %1" : "+v"(A), "+v"(C));
        asm volatile("v_permlane32_swap_b32 %0, %1" : "+v"(B), "+v"(D));
        asm volatile("v_permlane16_swap_b32 %0, %1" : "+v"(A), "+v"(C));
        asm volatile("v_permlane16_swap_b32 %0, %1" : "+v"(B), "+v"(D));
        u32x4 pk = {A, B, C, D};
        pa[nt] = __builtin_bit_cast(bf16x8, pk);
      }
#pragma unroll
      for (int dt = 0; dt < 4; ++dt) {
        int d = dt * 16 + c16;
        int vc = d * 8 + ((ksq * 4 + quad) ^ (d & 7));
        bf16x8 vf = *(const bf16x8*)(Vb + vc * 16);
#pragma unroll
        for (int mq = 0; mq < 2; ++mq)
          o[mq][dt] = __builtin_amdgcn_mfma_f32_16x16x32_bf16(pa[mq], vf,
                                                              o[mq][dt], 0, 0, 0);
      }
    }
    __syncthreads();
  }

  float linv[2] = {1.0f / lrow[0], 1.0f / lrow[1]};
  if (slot < 0) {
    // direct output
#pragma unroll
    for (int mq = 0; mq < 2; ++mq)
#pragma unroll
      for (int r = 0; r < 4; ++r) {
        float li = __shfl(linv[mq], quad * 4 + r);
        int q = q0 + w * 32 + mq * 16 + quad * 4 + r;
#pragma unroll
        for (int dt = 0; dt < 4; ++dt)
          aout[(size_t)(b * Tn + q) * 1024 + h * 64 + dt * 16 + c16] =
              f2bf_rne(o[mq][dt][r] * li);
      }
  } else {
    // partial: normalized O + (m, l) per row (m in log2 domain)
    int ps = slot * 32 + bh;
#pragma unroll
    for (int mq = 0; mq < 2; ++mq)
#pragma unroll
      for (int r = 0; r < 4; ++r) {
        float li = __shfl(linv[mq], quad * 4 + r);
        int qr = w * 32 + mq * 16 + quad * 4 + r;
#pragma unroll
        for (int dt = 0; dt < 4; ++dt)
          Op[((size_t)ps * 128 + qr) * 64 + dt * 16 + c16] =
              f2bf_rne(o[mq][dt][r] * li);
      }
    if (quad == 0) {
#pragma unroll
      for (int nt = 0; nt < 2; ++nt) {
        int qr = w * 32 + nt * 16 + c16;
        ml[((size_t)ps * 128 + qr) * 2] = mrow[nt];
        ml[((size_t)ps * 128 + qr) * 2 + 1] = lrow[nt];
      }
    }
  }
}

// ---------------- combine split partials (m in log2 domain, n-way) ----------
__global__ __launch_bounds__(256) void combine_kernel(const u16* __restrict__ Op,
                                                      const float* __restrict__ ml,
                                                      u16* __restrict__ aout) {
  int qt = 6 + (blockIdx.x >> 5);
  int bh = blockIdx.x & 31;
  int b = bh >> 4, h = bh & 15;
  int2 cb = comb_tab[qt - 6];
  int base = cb.x, n = cb.y;
  int d = threadIdx.x & 63, rq = threadIdx.x >> 6;
  for (int r = 0; r < 32; ++r) {
    int row = rq * 32 + r;
    float mv[3], lv[3], ov[3];
#pragma unroll
    for (int i = 0; i < 3; ++i) {
      int ps = (base + (i < n ? i : 0)) * 32 + bh;
      bool valid = i < n;
      mv[i] = valid ? ml[((size_t)ps * 128 + row) * 2] : -1e30f;
      lv[i] = valid ? ml[((size_t)ps * 128 + row) * 2 + 1] : 0.f;
      ov[i] = valid ? bf2f(Op[((size_t)ps * 128 + row) * 64 + d]) : 0.f;
    }
    float M = fmaxf(fmaxf(mv[0], mv[1]), mv[2]);
    float w0 = fexp2(mv[0] - M) * lv[0];
    float w1 = fexp2(mv[1] - M) * lv[1];
    float w2 = fexp2(mv[2] - M) * lv[2];
    float inv = 1.0f / (w0 + w1 + w2);
    aout[(size_t)(b * Tn + qt * 128 + row) * 1024 + h * 64 + d] =
        f2bf_rne((w0 * ov[0] + w1 * ov[1] + w2 * ov[2]) * inv);
  }
}

extern "C" void kernel_launch(void* const* d_in, const int* in_sizes, int n_in,
                              void* d_out, int out_size, void* d_ws, size_t ws_size,
                              hipStream_t stream) {
  const float* x = (const float*)d_in[0];
  // d_in[1] = causal mask: tril, implemented analytically — never read
  const float* ln_s = (const float*)d_in[2];
  const float* ln_b = (const float*)d_in[3];
  const float* qkv_w = (const float*)d_in[4];
  const float* qkv_b = (const float*)d_in[5];
  const float* proj_w = (const float*)d_in[6];
  const float* proj_b = (const float*)d_in[7];
  float* out = (float*)d_out;
  char* ws = (char*)d_ws;

  u16* xn = (u16*)ws;                       // 8 MiB  [4096][1024]
  u16* wqkv = (u16*)(ws + (8ull << 20));    // 6 MiB  [3072][1024]
  u16* wproj = (u16*)(ws + (14ull << 20));  // 2 MiB  [1024][1024]
  u16* qkvm = (u16*)(ws + (16ull << 20));   // 24 MiB [4096][3072]
  u16* attn = (u16*)(ws + (40ull << 20));   // 8 MiB  [4096][1024]
  u16* vt = (u16*)(ws + (48ull << 20));     // 8 MiB  [32][64][2048]
  // partials alias xn/wqkv (dead after QKV GEMM):
  u16* Op = (u16*)ws;                        // 12.5 MiB [25*32][128][64] bf16
  float* ml = (float*)(ws + (13ull << 20));  // 800 KiB  [25*32][128][2] f32

  ln_kernel<<<Mrows, 256, 0, stream>>>(x, ln_s, ln_b, xn);
  transpose_cast2<<<dim3(128, 32), dim3(32, 8), 0, stream>>>(qkv_w, wqkv, proj_w,
                                                             wproj);
  gemm_kernel<false, true><<<dim3(24, 32), 256, 0, stream>>>(xn, wqkv, qkv_b, qkvm,
                                                             3072, 1024);
  vt_prep<<<dim3(64, 2, 32), dim3(32, 8), 0, stream>>>(qkvm, vt);
  flash_kernel<<<992, 256, 0, stream>>>(qkvm, vt, attn, Op, ml);
  combine_kernel<<<320, 256, 0, stream>>>(Op, ml, attn);
  gemm_kernel<true, false><<<dim3(8, 32), 256, 0, stream>>>(attn, wproj, proj_b, out,
                                                            1024, 1024);
}